// Round 7
// baseline (536.346 us; speedup 1.0000x reference)
//
#include <hip/hip_runtime.h>

// Problem: x [32,3,512,512] fp32, 30 Perona-Malik iterations, expand to 3ch.
#define BATCH 32
#define HGT 512
#define WID 512
#define PLANE (HGT * WID)            // 262144
#define NPIX (BATCH * PLANE)         // 8388608
#define BSTRIDE (3 * PLANE)          // batch stride in x and d_out
#define NQUAD (NPIX / 4)

// Fused-slab geometry: 1024-thread block owns a 64-row slab (+S halo rows
// each side). 256 blocks = exactly 1 per CU, zero tail. 16 strips per block,
// each strip = ONE WAVE (64 lanes x two 4-wide segments = full 512-col row).
#define RSLAB 64
#define SLABS (HGT / RSLAB)          // 8
#define FBLOCKS (BATCH * SLABS)      // 256
#define FT 1024
#define MAXN 5                       // max rows per strip per step

__device__ __forceinline__ float4 ld4(const float* p) {
    return *reinterpret_cast<const float4*>(p);
}
__device__ __forceinline__ void st4(float* p, float4 v) {
    *reinterpret_cast<float4*>(p) = v;
}

// phi(d) = d / (1 + d^2/k^2); g even -> undirected edge flux shared with
// opposite signs by its two endpoint pixels.
__device__ __forceinline__ float pm_flux(float d, float ik2) {
    return d * __builtin_amdgcn_rcpf(fmaf(d * d, ik2, 1.f));
}

__device__ __forceinline__ void level_flux(const float a[6], const float b[6],
                                           float vF[4], float seF[5], float swF[5],
                                           float ik2) {
#pragma unroll
    for (int j = 0; j < 4; ++j) vF[j] = pm_flux(b[j + 1] - a[j + 1], ik2);
#pragma unroll
    for (int i = 0; i < 5; ++i) seF[i] = pm_flux(b[i + 1] - a[i], ik2);
#pragma unroll
    for (int i = 0; i < 5; ++i) swF[i] = pm_flux(b[i] - a[i + 1], ik2);
}

// Load one LDS row as two 6-wide segments: A = cols [4o-1, 4o+5),
// B = cols [256+4o-1, 256+4o+5). Interior loads are consecutive-lane
// ds_read_b128 (bank-balanced); edge columns come from wave shuffles
// (strip == wave, lanes lockstep). Image-boundary cols -> 0.
__device__ __forceinline__ void load_row2(const float* __restrict__ buf, int row, int o,
                                          float rA[6], float rB[6]) {
    const float* p = buf + row * WID + (o << 2);
    float4 a = ld4(p);
    float4 b = ld4(p + 256);
    float aW63 = __shfl(a.w, 63);        // col 255 (for B's left edge at lane 0)
    float bX0  = __shfl(b.x, 0);         // col 256 (for A's right edge at lane 63)
    float lA   = __shfl_up(a.w, 1);      // lane o-1's col 4o-1
    float rAr  = __shfl_down(a.x, 1);    // lane o+1's col 4o+4
    float lB   = __shfl_up(b.w, 1);
    float rBr  = __shfl_down(b.x, 1);
    rA[0] = (o == 0) ? 0.f : lA;
    rA[1] = a.x; rA[2] = a.y; rA[3] = a.z; rA[4] = a.w;
    rA[5] = (o == 63) ? bX0 : rAr;
    rB[0] = (o == 0) ? aW63 : lB;
    rB[1] = b.x; rB[2] = b.y; rB[3] = b.z; rB[4] = b.w;
    rB[5] = (o == 63) ? 0.f : rBr;
}

// Rolling per-segment state: current row m + fluxes to the row above.
struct SegState {
    float m[6];
    float pV[4], pSE[5], pSW[5];
};

__device__ __forceinline__ void seg_init(SegState& S_, const float a6[6],
                                         const float m6[6], float ik2) {
#pragma unroll
    for (int t = 0; t < 6; ++t) S_.m[t] = m6[t];
    level_flux(a6, m6, S_.pV, S_.pSE, S_.pSW, ik2);
}

__device__ __forceinline__ float4 seg_step(SegState& S_, const float d6[6],
                                           float delta, float ik2) {
    float hF[5];
#pragma unroll
    for (int t = 0; t < 5; ++t) hF[t] = pm_flux(S_.m[t + 1] - S_.m[t], ik2);
    float cV[4], cSE[5], cSW[5];
    level_flux(S_.m, d6, cV, cSE, cSW, ik2);
    float o[4];
#pragma unroll
    for (int j = 0; j < 4; ++j) {
        float axial = cV[j] - S_.pV[j] + hF[j + 1] - hF[j];
        float diag  = cSE[j + 1] + cSW[j] - S_.pSE[j] - S_.pSW[j + 1];
        o[j] = fmaf(delta, fmaf(0.5f, diag, axial), S_.m[j + 1]);
    }
#pragma unroll
    for (int t = 0; t < 6; ++t) S_.m[t] = d6[t];
#pragma unroll
    for (int j = 0; j < 4; ++j) S_.pV[j] = cV[j];
#pragma unroll
    for (int t = 0; t < 5; ++t) { S_.pSE[t] = cSE[t]; S_.pSW[t] = cSW[t]; }
    return make_float4(o[0], o[1], o[2], o[3]);
}

// ---------------------------------------------------------------------------
// Fused-S kernel. MODE 0: src = x (lum on load). MODE 1: u -> u.
// MODE 2: final, expand into 3 output planes.
// In-place LDS trapezoid; interior rows written back immediately (only read
// by the owning wave, lockstep-safe); 2 boundary rows per strip held in regs
// and written between the two barriers.
// ---------------------------------------------------------------------------
template <int MODE, int S>
__global__ __launch_bounds__(FT, 4)
void pm_fusedk(const float* __restrict__ src, int sstr,
               float* __restrict__ dst, int dstr,
               const float* __restrict__ pdelta, const float* __restrict__ pkappa,
               const float* __restrict__ Wexp, const float* __restrict__ bexp) {
    constexpr int LR = RSLAB + 2 * S;
    extern __shared__ float buf[];            // LR x 512

    const int img   = blockIdx.x >> 3;        // / SLABS
    const int slab  = blockIdx.x & (SLABS - 1);
    const int H0    = slab * RSLAB;
    const int tid   = threadIdx.x;
    const int strip = tid >> 6;               // 0..15 == wave id
    const int o     = tid & 63;               // lane == quad index

    const float delta = *pdelta;
    const float kappa = *pkappa;
    const float ik2 = __builtin_amdgcn_rcpf(kappa * kappa);

    // ---- load LR rows (rows outside image -> 0) ----
    const float* sb = src + (size_t)img * sstr;
#pragma unroll
    for (int i = tid; i < LR * (WID / 4); i += FT) {
        int row = i >> 7;
        int q   = i & 127;
        int g = H0 - S + row;
        float4 v = make_float4(0.f, 0.f, 0.f, 0.f);
        if ((unsigned)g < (unsigned)HGT) {
            const float* p = sb + g * WID + (q << 2);
            if (MODE == 0) {
                float4 r = ld4(p), gg = ld4(p + PLANE), bb = ld4(p + 2 * PLANE);
                v.x = fmaf(0.299f, r.x, fmaf(0.587f, gg.x, 0.114f * bb.x));
                v.y = fmaf(0.299f, r.y, fmaf(0.587f, gg.y, 0.114f * bb.y));
                v.z = fmaf(0.299f, r.z, fmaf(0.587f, gg.z, 0.114f * bb.z));
                v.w = fmaf(0.299f, r.w, fmaf(0.587f, gg.w, 0.114f * bb.w));
            } else {
                v = ld4(p);
            }
        }
        st4(buf + row * WID + (q << 2), v);
    }
    __syncthreads();

    float s0c = 0.f, s1c = 0.f, s2c = 0.f, b0c = 0.f, b1c = 0.f, b2c = 0.f;
    if (MODE == 2) {
        s0c = Wexp[0] + Wexp[1] + Wexp[2];
        s1c = Wexp[3] + Wexp[4] + Wexp[5];
        s2c = Wexp[6] + Wexp[7] + Wexp[8];
        b0c = bexp[0]; b1c = bexp[1]; b2c = bexp[2];
    }

    float* db = dst + (size_t)img * dstr;

#pragma unroll
    for (int s = 0; s < S; ++s) {
        const int L0 = s + 1, L1 = LR - 1 - s;
        const int tot = L1 - L0;                      // >= 64 always
        const int bse = tot >> 4, rem = tot & 15;
        const int n   = bse + (strip < rem ? 1 : 0);  // 4..5, wave-uniform
        const int st0 = L0 + strip * bse + (strip < rem ? strip : rem);
        const bool fin = (s == S - 1);

        SegState SA, SB;
        {
            float a6[6], b6[6], mA[6], mB[6];
            load_row2(buf, st0 - 1, o, a6, b6);
            load_row2(buf, st0, o, mA, mB);
            seg_init(SA, a6, mA, ik2);
            seg_init(SB, b6, mB, ik2);
        }
        float4 fA = make_float4(0, 0, 0, 0), fB = fA, lA4 = fA, lB4 = fA;

#pragma unroll
        for (int i = 0; i < MAXN; ++i) {
            if (i < n) {
                float dA[6], dB[6];
                load_row2(buf, st0 + i + 1, o, dA, dB);
                float4 rA = seg_step(SA, dA, delta, ik2);
                float4 rB = seg_step(SB, dB, delta, ik2);
                const int g = H0 - S + st0 + i;
                if ((unsigned)g >= (unsigned)HGT) {
                    rA = make_float4(0, 0, 0, 0);
                    rB = make_float4(0, 0, 0, 0);
                }
                if (fin) {
                    float* p = db + (size_t)g * WID + (o << 2);
                    if (MODE == 2) {
                        st4(p, make_float4(fmaf(s0c, rA.x, b0c), fmaf(s0c, rA.y, b0c),
                                           fmaf(s0c, rA.z, b0c), fmaf(s0c, rA.w, b0c)));
                        st4(p + 256, make_float4(fmaf(s0c, rB.x, b0c), fmaf(s0c, rB.y, b0c),
                                                 fmaf(s0c, rB.z, b0c), fmaf(s0c, rB.w, b0c)));
                        st4(p + PLANE,
                            make_float4(fmaf(s1c, rA.x, b1c), fmaf(s1c, rA.y, b1c),
                                        fmaf(s1c, rA.z, b1c), fmaf(s1c, rA.w, b1c)));
                        st4(p + PLANE + 256,
                            make_float4(fmaf(s1c, rB.x, b1c), fmaf(s1c, rB.y, b1c),
                                        fmaf(s1c, rB.z, b1c), fmaf(s1c, rB.w, b1c)));
                        st4(p + 2 * PLANE,
                            make_float4(fmaf(s2c, rA.x, b2c), fmaf(s2c, rA.y, b2c),
                                        fmaf(s2c, rA.z, b2c), fmaf(s2c, rA.w, b2c)));
                        st4(p + 2 * PLANE + 256,
                            make_float4(fmaf(s2c, rB.x, b2c), fmaf(s2c, rB.y, b2c),
                                        fmaf(s2c, rB.z, b2c), fmaf(s2c, rB.w, b2c)));
                    } else {
                        st4(p, rA);
                        st4(p + 256, rB);
                    }
                } else if (i == 0) {
                    fA = rA; fB = rB;                 // strip-top boundary: hold
                } else if (i == n - 1) {
                    lA4 = rA; lB4 = rB;               // strip-bottom boundary: hold
                } else {
                    // interior: only this wave reads this row; lanes lockstep
                    // already loaded it -> safe to overwrite now.
                    float* p = buf + (st0 + i) * WID + (o << 2);
                    st4(p, rA);
                    st4(p + 256, rB);
                }
            }
        }
        if (!fin) {
            __syncthreads();                          // all strips done reading
            {
                float* p = buf + st0 * WID + (o << 2);
                st4(p, fA);
                st4(p + 256, fB);
            }
            {
                float* p = buf + (st0 + n - 1) * WID + (o << 2);
                st4(p, lA4);
                st4(p + 256, lB4);
            }
            __syncthreads();                          // boundary rows visible
        }
    }
}

// ---------------------------------------------------------------------------
// Fallback expand: reads u from usrc (own pixel), writes 3 planes of out.
// ---------------------------------------------------------------------------
__global__ void expand_from(const float* __restrict__ usrc, int ustr,
                            float* __restrict__ out,
                            const float* __restrict__ Wexp,
                            const float* __restrict__ bexp) {
    int idx = blockIdx.x * blockDim.x + threadIdx.x;
    if (idx >= NQUAD) return;
    int b = idx / (PLANE / 4);
    int off = (idx - b * (PLANE / 4)) * 4;

    float4 u = ld4(usrc + (size_t)b * ustr + off);
    float s0 = Wexp[0] + Wexp[1] + Wexp[2];
    float s1 = Wexp[3] + Wexp[4] + Wexp[5];
    float s2 = Wexp[6] + Wexp[7] + Wexp[8];
    float b0 = bexp[0], b1 = bexp[1], b2 = bexp[2];

    size_t base = (size_t)b * BSTRIDE + off;
    st4(out + base, make_float4(fmaf(s0, u.x, b0), fmaf(s0, u.y, b0),
                                fmaf(s0, u.z, b0), fmaf(s0, u.w, b0)));
    st4(out + base + PLANE, make_float4(fmaf(s1, u.x, b1), fmaf(s1, u.y, b1),
                                        fmaf(s1, u.z, b1), fmaf(s1, u.w, b1)));
    st4(out + base + 2 * PLANE, make_float4(fmaf(s2, u.x, b2), fmaf(s2, u.y, b2),
                                            fmaf(s2, u.z, b2), fmaf(s2, u.w, b2)));
}

extern "C" void kernel_launch(void* const* d_in, const int* in_sizes, int n_in,
                              void* d_out, int out_size, void* d_ws, size_t ws_size,
                              hipStream_t stream) {
    const float* x      = (const float*)d_in[0];
    const float* pdelta = (const float*)d_in[1];
    const float* pkappa = (const float*)d_in[2];
    const float* Wexp   = (const float*)d_in[3];
    const float* bexp   = (const float*)d_in[4];
    float* out = (float*)d_out;

    const int LDS4 = (RSLAB + 8) * WID * 4;   // 72 rows = 147456 B
    const int LDS2 = (RSLAB + 4) * WID * 4;   // 68 rows = 139264 B

    const size_t need = (size_t)2 * NPIX * sizeof(float);   // 64 MB
    if (ws_size >= need) {
        // 8 dispatches: [lum+steps1-4], 6x[4 steps] (5-28), [steps29-30+expand].
        float* uA = (float*)d_ws;
        float* uB = uA + NPIX;
        pm_fusedk<0, 4><<<FBLOCKS, FT, LDS4, stream>>>(
            x, BSTRIDE, uA, PLANE, pdelta, pkappa, Wexp, bexp);
        float* s = uA;
        float* d = uB;
        for (int k = 0; k < 6; ++k) {
            pm_fusedk<1, 4><<<FBLOCKS, FT, LDS4, stream>>>(
                s, PLANE, d, PLANE, pdelta, pkappa, Wexp, bexp);
            float* t = s; s = d; d = t;
        }
        // u28 is in s. Final 2 steps + expand; d_out written exactly once.
        pm_fusedk<2, 2><<<FBLOCKS, FT, LDS2, stream>>>(
            s, PLANE, out, BSTRIDE, pdelta, pkappa, Wexp, bexp);
    } else {
        // Fallback: ping-pong in d_out planes 0/1, separate expand.
        float* uA = out;            // plane 0
        float* uB = out + PLANE;    // plane 1
        pm_fusedk<0, 4><<<FBLOCKS, FT, LDS4, stream>>>(
            x, BSTRIDE, uA, BSTRIDE, pdelta, pkappa, Wexp, bexp);
        float* s = uA;
        float* d = uB;
        for (int k = 0; k < 6; ++k) {
            pm_fusedk<1, 4><<<FBLOCKS, FT, LDS4, stream>>>(
                s, BSTRIDE, d, BSTRIDE, pdelta, pkappa, Wexp, bexp);
            float* t = s; s = d; d = t;
        }
        // u28 in s; 2 more steps into d, then expand from d.
        pm_fusedk<1, 2><<<FBLOCKS, FT, LDS2, stream>>>(
            s, BSTRIDE, d, BSTRIDE, pdelta, pkappa, Wexp, bexp);
        const int block = 256;
        const int grid_q = (NQUAD + block - 1) / block;
        expand_from<<<grid_q, block, 0, stream>>>(d, BSTRIDE, out, Wexp, bexp);
    }
}

// Round 8
// 395.874 us; speedup vs baseline: 1.3548x; 1.3548x over previous
//
#include <hip/hip_runtime.h>

// Problem: x [32,3,512,512] fp32, 30 Perona-Malik iterations, expand to 3ch.
#define BATCH 32
#define HGT 512
#define WID 512
#define PLANE (HGT * WID)            // 262144
#define NPIX (BATCH * PLANE)         // 8388608
#define BSTRIDE (3 * PLANE)          // batch stride in x and d_out
#define NQUAD (NPIX / 4)

// Fused-slab geometry: 512-thread block (8 waves) owns a 32-row slab with
// S halo rows each side. Static LDS = (32+2S)*512*4B (80 KB at S=4) ->
// exactly 2 blocks/CU, 512 blocks = 2/CU, zero tail. One wave = one strip,
// covering full 512-col rows as two 64-lane x 4-col segments.
#define RSLAB 32
#define SLABS (HGT / RSLAB)          // 16
#define FBLOCKS (BATCH * SLABS)      // 512
#define FT 512
#define NW 8                         // waves per block

__device__ __forceinline__ float4 ld4(const float* p) {
    return *reinterpret_cast<const float4*>(p);
}
__device__ __forceinline__ void st4(float* p, float4 v) {
    *reinterpret_cast<float4*>(p) = v;
}

// phi(d) = d / (1 + d^2/k^2); g even -> undirected edge flux shared with
// opposite signs by its two endpoint pixels.
__device__ __forceinline__ float pm_flux(float d, float ik2) {
    return d * __builtin_amdgcn_rcpf(fmaf(d * d, ik2, 1.f));
}

__device__ __forceinline__ void level_flux(const float a[6], const float b[6],
                                           float vF[4], float seF[5], float swF[5],
                                           float ik2) {
#pragma unroll
    for (int j = 0; j < 4; ++j) vF[j] = pm_flux(b[j + 1] - a[j + 1], ik2);
#pragma unroll
    for (int i = 0; i < 5; ++i) seF[i] = pm_flux(b[i + 1] - a[i], ik2);
#pragma unroll
    for (int i = 0; i < 5; ++i) swF[i] = pm_flux(b[i] - a[i + 1], ik2);
}

// Load one LDS row as two 6-wide segments: A = cols [4o-1,4o+5),
// B = cols [256+4o-1,256+4o+5). Interior data via consecutive-lane
// ds_read_b128 (bank-balanced, conflict-free); edge columns via wave
// shuffles (one wave per strip, lanes lockstep). Image-edge cols -> 0.
__device__ __forceinline__ void load_row2(const float* __restrict__ buf, int row, int o,
                                          float rA[6], float rB[6]) {
    const float* p = buf + row * WID + (o << 2);
    float4 a = ld4(p);
    float4 b = ld4(p + 256);
    float aW63 = __shfl(a.w, 63);        // col 255 (B's left edge at lane 0)
    float bX0  = __shfl(b.x, 0);         // col 256 (A's right edge at lane 63)
    float lA   = __shfl_up(a.w, 1);
    float rAr  = __shfl_down(a.x, 1);
    float lB   = __shfl_up(b.w, 1);
    float rBr  = __shfl_down(b.x, 1);
    rA[0] = (o == 0) ? 0.f : lA;
    rA[1] = a.x; rA[2] = a.y; rA[3] = a.z; rA[4] = a.w;
    rA[5] = (o == 63) ? bX0 : rAr;
    rB[0] = (o == 0) ? aW63 : lB;
    rB[1] = b.x; rB[2] = b.y; rB[3] = b.z; rB[4] = b.w;
    rB[5] = (o == 63) ? 0.f : rBr;
}

// Rolling per-segment state: current row m + fluxes to the row above.
struct SegState {
    float m[6];
    float pV[4], pSE[5], pSW[5];
};

__device__ __forceinline__ void seg_init(SegState& S_, const float a6[6],
                                         const float m6[6], float ik2) {
#pragma unroll
    for (int t = 0; t < 6; ++t) S_.m[t] = m6[t];
    level_flux(a6, m6, S_.pV, S_.pSE, S_.pSW, ik2);
}

__device__ __forceinline__ float4 seg_step(SegState& S_, const float d6[6],
                                           float delta, float ik2) {
    float hF[5];
#pragma unroll
    for (int t = 0; t < 5; ++t) hF[t] = pm_flux(S_.m[t + 1] - S_.m[t], ik2);
    float cV[4], cSE[5], cSW[5];
    level_flux(S_.m, d6, cV, cSE, cSW, ik2);
    float o[4];
#pragma unroll
    for (int j = 0; j < 4; ++j) {
        float axial = cV[j] - S_.pV[j] + hF[j + 1] - hF[j];
        float diag  = cSE[j + 1] + cSW[j] - S_.pSE[j] - S_.pSW[j + 1];
        o[j] = fmaf(delta, fmaf(0.5f, diag, axial), S_.m[j + 1]);
    }
#pragma unroll
    for (int t = 0; t < 6; ++t) S_.m[t] = d6[t];
#pragma unroll
    for (int j = 0; j < 4; ++j) S_.pV[j] = cV[j];
#pragma unroll
    for (int t = 0; t < 5; ++t) { S_.pSE[t] = cSE[t]; S_.pSW[t] = cSW[t]; }
    return make_float4(o[0], o[1], o[2], o[3]);
}

// ---------------------------------------------------------------------------
// Fused-S kernel. MODE 0: src = x (lum on load). MODE 1: u -> u.
// MODE 2: final, expand into 3 output planes.
// In-place LDS trapezoid: interior rows written back immediately (private to
// the owning wave, lockstep-safe); the 2 strip-boundary rows are held in regs
// and written between the two barriers. Final step writes global directly.
// ---------------------------------------------------------------------------
template <int MODE, int S>
__global__ __launch_bounds__(FT, 4)
void pm_fusedk(const float* __restrict__ src, int sstr,
               float* __restrict__ dst, int dstr,
               const float* __restrict__ pdelta, const float* __restrict__ pkappa,
               const float* __restrict__ Wexp, const float* __restrict__ bexp) {
    constexpr int LR = RSLAB + 2 * S;
    __shared__ float buf[LR * WID];           // static: compiler sees occupancy

    const int img   = blockIdx.x >> 4;        // / SLABS
    const int slab  = blockIdx.x & (SLABS - 1);
    const int H0    = slab * RSLAB;
    const int tid   = threadIdx.x;
    const int strip = tid >> 6;               // 0..7 == wave id
    const int o     = tid & 63;

    const float delta = *pdelta;
    const float kappa = *pkappa;
    const float ik2 = __builtin_amdgcn_rcpf(kappa * kappa);

    // ---- load LR rows (rows outside image -> 0) ----
    const float* sb = src + (size_t)img * sstr;
    for (int i = tid; i < LR * (WID / 4); i += FT) {
        int row = i >> 7;
        int q   = i & 127;
        int g = H0 - S + row;
        float4 v = make_float4(0.f, 0.f, 0.f, 0.f);
        if ((unsigned)g < (unsigned)HGT) {
            const float* p = sb + g * WID + (q << 2);
            if (MODE == 0) {
                float4 r = ld4(p), gg = ld4(p + PLANE), bb = ld4(p + 2 * PLANE);
                v.x = fmaf(0.299f, r.x, fmaf(0.587f, gg.x, 0.114f * bb.x));
                v.y = fmaf(0.299f, r.y, fmaf(0.587f, gg.y, 0.114f * bb.y));
                v.z = fmaf(0.299f, r.z, fmaf(0.587f, gg.z, 0.114f * bb.z));
                v.w = fmaf(0.299f, r.w, fmaf(0.587f, gg.w, 0.114f * bb.w));
            } else {
                v = ld4(p);
            }
        }
        st4(buf + row * WID + (q << 2), v);
    }
    __syncthreads();

    float s0c = 0.f, s1c = 0.f, s2c = 0.f, b0c = 0.f, b1c = 0.f, b2c = 0.f;
    if (MODE == 2) {
        s0c = Wexp[0] + Wexp[1] + Wexp[2];
        s1c = Wexp[3] + Wexp[4] + Wexp[5];
        s2c = Wexp[6] + Wexp[7] + Wexp[8];
        b0c = bexp[0]; b1c = bexp[1]; b2c = bexp[2];
    }

    float* db = dst + (size_t)img * dstr;

    for (int s = 0; s < S; ++s) {
        const int tot = LR - 2 - 2 * s;               // rows to compute
        const int bse = tot >> 3, rem = tot & 7;
        const int n   = bse + (strip < rem ? 1 : 0);  // wave-uniform
        const int st0 = s + 1 + strip * bse + (strip < rem ? strip : rem);
        const bool fin = (s == S - 1);

        SegState SA, SB;
        {
            float a6[6], b6[6], mA[6], mB[6];
            load_row2(buf, st0 - 1, o, a6, b6);
            load_row2(buf, st0, o, mA, mB);
            seg_init(SA, a6, mA, ik2);
            seg_init(SB, b6, mB, ik2);
        }
        float4 fA = make_float4(0, 0, 0, 0), fB = fA, lA4 = fA, lB4 = fA;

        for (int i = 0; i < n; ++i) {
            float dA[6], dB[6];
            load_row2(buf, st0 + i + 1, o, dA, dB);
            float4 rA = seg_step(SA, dA, delta, ik2);
            float4 rB = seg_step(SB, dB, delta, ik2);
            const int g = H0 - S + st0 + i;
            if ((unsigned)g >= (unsigned)HGT) {
                rA = make_float4(0, 0, 0, 0);
                rB = make_float4(0, 0, 0, 0);
            }
            if (fin) {
                float* p = db + (size_t)g * WID + (o << 2);
                if (MODE == 2) {
                    st4(p, make_float4(fmaf(s0c, rA.x, b0c), fmaf(s0c, rA.y, b0c),
                                       fmaf(s0c, rA.z, b0c), fmaf(s0c, rA.w, b0c)));
                    st4(p + 256, make_float4(fmaf(s0c, rB.x, b0c), fmaf(s0c, rB.y, b0c),
                                             fmaf(s0c, rB.z, b0c), fmaf(s0c, rB.w, b0c)));
                    st4(p + PLANE,
                        make_float4(fmaf(s1c, rA.x, b1c), fmaf(s1c, rA.y, b1c),
                                    fmaf(s1c, rA.z, b1c), fmaf(s1c, rA.w, b1c)));
                    st4(p + PLANE + 256,
                        make_float4(fmaf(s1c, rB.x, b1c), fmaf(s1c, rB.y, b1c),
                                    fmaf(s1c, rB.z, b1c), fmaf(s1c, rB.w, b1c)));
                    st4(p + 2 * PLANE,
                        make_float4(fmaf(s2c, rA.x, b2c), fmaf(s2c, rA.y, b2c),
                                    fmaf(s2c, rA.z, b2c), fmaf(s2c, rA.w, b2c)));
                    st4(p + 2 * PLANE + 256,
                        make_float4(fmaf(s2c, rB.x, b2c), fmaf(s2c, rB.y, b2c),
                                    fmaf(s2c, rB.z, b2c), fmaf(s2c, rB.w, b2c)));
                } else {
                    st4(p, rA);
                    st4(p + 256, rB);
                }
            } else if (i == 0) {
                fA = rA; fB = rB;                     // strip-top boundary: hold
            } else if (i == n - 1) {
                lA4 = rA; lB4 = rB;                   // strip-bottom boundary: hold
            } else {
                // interior row: private to this wave, already consumed -> write now
                float* p = buf + (st0 + i) * WID + (o << 2);
                st4(p, rA);
                st4(p + 256, rB);
            }
        }
        if (!fin) {
            __syncthreads();                          // all strips done reading
            {
                float* p = buf + st0 * WID + (o << 2);
                st4(p, fA);
                st4(p + 256, fB);
            }
            {
                float* p = buf + (st0 + n - 1) * WID + (o << 2);
                st4(p, lA4);
                st4(p + 256, lB4);
            }
            __syncthreads();                          // boundary rows visible
        }
    }
}

// ---------------------------------------------------------------------------
// Fallback expand: reads u from usrc (own pixel), writes 3 planes of out.
// ---------------------------------------------------------------------------
__global__ void expand_from(const float* __restrict__ usrc, int ustr,
                            float* __restrict__ out,
                            const float* __restrict__ Wexp,
                            const float* __restrict__ bexp) {
    int idx = blockIdx.x * blockDim.x + threadIdx.x;
    if (idx >= NQUAD) return;
    int b = idx / (PLANE / 4);
    int off = (idx - b * (PLANE / 4)) * 4;

    float4 u = ld4(usrc + (size_t)b * ustr + off);
    float s0 = Wexp[0] + Wexp[1] + Wexp[2];
    float s1 = Wexp[3] + Wexp[4] + Wexp[5];
    float s2 = Wexp[6] + Wexp[7] + Wexp[8];
    float b0 = bexp[0], b1 = bexp[1], b2 = bexp[2];

    size_t base = (size_t)b * BSTRIDE + off;
    st4(out + base, make_float4(fmaf(s0, u.x, b0), fmaf(s0, u.y, b0),
                                fmaf(s0, u.z, b0), fmaf(s0, u.w, b0)));
    st4(out + base + PLANE, make_float4(fmaf(s1, u.x, b1), fmaf(s1, u.y, b1),
                                        fmaf(s1, u.z, b1), fmaf(s1, u.w, b1)));
    st4(out + base + 2 * PLANE, make_float4(fmaf(s2, u.x, b2), fmaf(s2, u.y, b2),
                                            fmaf(s2, u.z, b2), fmaf(s2, u.w, b2)));
}

extern "C" void kernel_launch(void* const* d_in, const int* in_sizes, int n_in,
                              void* d_out, int out_size, void* d_ws, size_t ws_size,
                              hipStream_t stream) {
    const float* x      = (const float*)d_in[0];
    const float* pdelta = (const float*)d_in[1];
    const float* pkappa = (const float*)d_in[2];
    const float* Wexp   = (const float*)d_in[3];
    const float* bexp   = (const float*)d_in[4];
    float* out = (float*)d_out;

    const size_t need = (size_t)2 * NPIX * sizeof(float);   // 64 MB
    if (ws_size >= need) {
        // 8 dispatches: [lum+steps1-4], 6x[4 steps] (5-28), [steps29-30+expand].
        float* uA = (float*)d_ws;
        float* uB = uA + NPIX;
        pm_fusedk<0, 4><<<FBLOCKS, FT, 0, stream>>>(
            x, BSTRIDE, uA, PLANE, pdelta, pkappa, Wexp, bexp);
        float* s = uA;
        float* d = uB;
        for (int k = 0; k < 6; ++k) {
            pm_fusedk<1, 4><<<FBLOCKS, FT, 0, stream>>>(
                s, PLANE, d, PLANE, pdelta, pkappa, Wexp, bexp);
            float* t = s; s = d; d = t;
        }
        // u28 is in s. Final 2 steps + expand; d_out written exactly once.
        pm_fusedk<2, 2><<<FBLOCKS, FT, 0, stream>>>(
            s, PLANE, out, BSTRIDE, pdelta, pkappa, Wexp, bexp);
    } else {
        // Fallback: ping-pong in d_out planes 0/1, separate expand.
        float* uA = out;            // plane 0
        float* uB = out + PLANE;    // plane 1
        pm_fusedk<0, 4><<<FBLOCKS, FT, 0, stream>>>(
            x, BSTRIDE, uA, BSTRIDE, pdelta, pkappa, Wexp, bexp);
        float* s = uA;
        float* d = uB;
        for (int k = 0; k < 6; ++k) {
            pm_fusedk<1, 4><<<FBLOCKS, FT, 0, stream>>>(
                s, BSTRIDE, d, BSTRIDE, pdelta, pkappa, Wexp, bexp);
            float* t = s; s = d; d = t;
        }
        // u28 in s; 2 more steps into d, then expand from d.
        pm_fusedk<1, 2><<<FBLOCKS, FT, 0, stream>>>(
            s, BSTRIDE, d, BSTRIDE, pdelta, pkappa, Wexp, bexp);
        const int block = 256;
        const int grid_q = (NQUAD + block - 1) / block;
        expand_from<<<grid_q, block, 0, stream>>>(d, BSTRIDE, out, Wexp, bexp);
    }
}

// Round 9
// 378.335 us; speedup vs baseline: 1.4177x; 1.0464x over previous
//
#include <hip/hip_runtime.h>

// Problem: x [32,3,512,512] fp32, 30 Perona-Malik iterations, expand to 3ch.
#define BATCH 32
#define HGT 512
#define WID 512
#define PLANE (HGT * WID)            // 262144
#define NPIX (BATCH * PLANE)         // 8388608
#define BSTRIDE (3 * PLANE)          // batch stride in x and d_out
#define NQUAD (NPIX / 4)

// Fused-slab geometry: 512-thread block (8 waves) owns a 32-row slab with S
// halo rows each side. Static LDS (32+2S)*512*4B (80 KB @ S=4) -> 2 blocks/CU,
// 512 blocks = zero tail. One wave = one row-strip; lane owns 8 CONTIGUOUS
// cols (cols 8o..8o+7), so a row is one 10-wide window: 2 ds_read_b128 +
// 2 shuffles per row (edge cols from neighbor lanes).
#define RSLAB 32
#define SLABS (HGT / RSLAB)          // 16
#define FBLOCKS (BATCH * SLABS)      // 512
#define FT 512
#define NW 8

__device__ __forceinline__ float4 ld4(const float* p) {
    return *reinterpret_cast<const float4*>(p);
}
__device__ __forceinline__ void st4(float* p, float4 v) {
    *reinterpret_cast<float4*>(p) = v;
}

// phi(d) = d / (1 + d^2/k^2); g even -> undirected edge flux shared with
// opposite signs by its two endpoint pixels.
__device__ __forceinline__ float pm_flux(float d, float ik2) {
    return d * __builtin_amdgcn_rcpf(fmaf(d * d, ik2, 1.f));
}

// Rolling row state: m = row data (10-wide window, cols 8o-1..8o+8),
// p* = fluxes between this row and the row ABOVE it.
struct RowState {
    float m[10];
    float pV[8], pSE[9], pSW[9];
};

// Load LDS row into a 10-wide window. Interior: 2 consecutive-lane
// ds_read_b128. Edges: wave shuffles (one wave per strip, lockstep).
__device__ __forceinline__ void load_row10(const float* __restrict__ buf, int row, int o,
                                           float m[10]) {
    const float* p = buf + row * WID + (o << 3);
    float4 lo = ld4(p);
    float4 hi = ld4(p + 4);
    float le = __shfl_up(hi.w, 1);      // lane o-1's col 8o-1
    float re = __shfl_down(lo.x, 1);    // lane o+1's col 8o+8
    m[0] = (o == 0) ? 0.f : le;
    m[1] = lo.x; m[2] = lo.y; m[3] = lo.z; m[4] = lo.w;
    m[5] = hi.x; m[6] = hi.y; m[7] = hi.z; m[8] = hi.w;
    m[9] = (o == 63) ? 0.f : re;
}

// Level fluxes between row a (upper) and row b (lower), written into b's p*.
__device__ __forceinline__ void level10(const float a[10], const float b[10],
                                        float vF[8], float seF[9], float swF[9],
                                        float ik2) {
#pragma unroll
    for (int j = 0; j < 8; ++j) vF[j] = pm_flux(b[j + 1] - a[j + 1], ik2);
#pragma unroll
    for (int i = 0; i < 9; ++i) seF[i] = pm_flux(b[i + 1] - a[i], ik2);
#pragma unroll
    for (int i = 0; i < 9; ++i) swF[i] = pm_flux(b[i] - a[i + 1], ik2);
}

// ---------------------------------------------------------------------------
// Fused-S kernel. MODE 0: src = x (lum on load). MODE 1: u -> u.
// MODE 2: final, expand into 3 output planes.
// In-place LDS trapezoid: interior rows written back immediately (private to
// the owning wave); the 2 strip-boundary rows held in regs and written
// between the two barriers. Final step writes global directly.
// ---------------------------------------------------------------------------
template <int MODE, int S>
__global__ __launch_bounds__(FT) __attribute__((amdgpu_waves_per_eu(4, 4)))
void pm_fusedk(const float* __restrict__ src, int sstr,
               float* __restrict__ dst, int dstr,
               const float* __restrict__ pdelta, const float* __restrict__ pkappa,
               const float* __restrict__ Wexp, const float* __restrict__ bexp) {
    constexpr int LR = RSLAB + 2 * S;
    __shared__ float buf[LR * WID];

    const int img  = blockIdx.x >> 4;         // / SLABS
    const int slab = blockIdx.x & (SLABS - 1);
    const int H0   = slab * RSLAB;
    const int tid  = threadIdx.x;
    const int wave = tid >> 6;                // 0..7
    const int o    = tid & 63;

    const float delta = *pdelta;
    const float kappa = *pkappa;
    const float ik2 = __builtin_amdgcn_rcpf(kappa * kappa);

    // ---- stage LR rows into LDS (rows outside image -> 0) ----
    const float* sb = src + (size_t)img * sstr;
    for (int i = tid; i < LR * (WID / 4); i += FT) {
        int row = i >> 7;
        int q   = i & 127;
        int g = H0 - S + row;
        float4 v = make_float4(0.f, 0.f, 0.f, 0.f);
        if ((unsigned)g < (unsigned)HGT) {
            const float* p = sb + g * WID + (q << 2);
            if (MODE == 0) {
                float4 r = ld4(p), gg = ld4(p + PLANE), bb = ld4(p + 2 * PLANE);
                v.x = fmaf(0.299f, r.x, fmaf(0.587f, gg.x, 0.114f * bb.x));
                v.y = fmaf(0.299f, r.y, fmaf(0.587f, gg.y, 0.114f * bb.y));
                v.z = fmaf(0.299f, r.z, fmaf(0.587f, gg.z, 0.114f * bb.z));
                v.w = fmaf(0.299f, r.w, fmaf(0.587f, gg.w, 0.114f * bb.w));
            } else {
                v = ld4(p);
            }
        }
        st4(buf + row * WID + (q << 2), v);
    }
    __syncthreads();

    float s0c = 0.f, s1c = 0.f, s2c = 0.f, b0c = 0.f, b1c = 0.f, b2c = 0.f;
    if (MODE == 2) {
        s0c = Wexp[0] + Wexp[1] + Wexp[2];
        s1c = Wexp[3] + Wexp[4] + Wexp[5];
        s2c = Wexp[6] + Wexp[7] + Wexp[8];
        b0c = bexp[0]; b1c = bexp[1]; b2c = bexp[2];
    }

    float* db = dst + (size_t)img * dstr;

    for (int s = 0; s < S; ++s) {
        const int tot = LR - 2 - 2 * s;
        const int bse = tot >> 3, rem = tot & 7;
        const int n   = bse + (wave < rem ? 1 : 0);        // 4..5, wave-uniform
        const int st0 = s + 1 + wave * bse + (wave < rem ? wave : rem);
        const bool fin = (s == S - 1);

        RowState A, B;
        {
            float a10[10];
            load_row10(buf, st0 - 1, o, a10);
            load_row10(buf, st0, o, A.m);
            level10(a10, A.m, A.pV, A.pSE, A.pSW, ik2);
        }
        float4 f0 = make_float4(0, 0, 0, 0), f1 = f0, l0 = f0, l1 = f0;

        // One row: load next row into NEXT (zero-copy roll), compute out row.
        auto do_row = [&](RowState& CUR, RowState& NEXT, int i) {
            load_row10(buf, st0 + i + 1, o, NEXT.m);
            float hF[9];
#pragma unroll
            for (int t = 0; t < 9; ++t) hF[t] = pm_flux(CUR.m[t + 1] - CUR.m[t], ik2);
            level10(CUR.m, NEXT.m, NEXT.pV, NEXT.pSE, NEXT.pSW, ik2);
            float o8[8];
#pragma unroll
            for (int j = 0; j < 8; ++j) {
                float axial = NEXT.pV[j] - CUR.pV[j] + hF[j + 1] - hF[j];
                float diag  = NEXT.pSE[j + 1] + NEXT.pSW[j]
                            - CUR.pSE[j] - CUR.pSW[j + 1];
                o8[j] = fmaf(delta, fmaf(0.5f, diag, axial), CUR.m[j + 1]);
            }
            const int g = H0 - S + st0 + i;
            if ((unsigned)g >= (unsigned)HGT) {
#pragma unroll
                for (int j = 0; j < 8; ++j) o8[j] = 0.f;
            }
            float4 r0 = make_float4(o8[0], o8[1], o8[2], o8[3]);
            float4 r1 = make_float4(o8[4], o8[5], o8[6], o8[7]);
            if (fin) {
                float* p = db + (size_t)g * WID + (o << 3);
                if (MODE == 2) {
                    st4(p, make_float4(fmaf(s0c, r0.x, b0c), fmaf(s0c, r0.y, b0c),
                                       fmaf(s0c, r0.z, b0c), fmaf(s0c, r0.w, b0c)));
                    st4(p + 4, make_float4(fmaf(s0c, r1.x, b0c), fmaf(s0c, r1.y, b0c),
                                           fmaf(s0c, r1.z, b0c), fmaf(s0c, r1.w, b0c)));
                    st4(p + PLANE,
                        make_float4(fmaf(s1c, r0.x, b1c), fmaf(s1c, r0.y, b1c),
                                    fmaf(s1c, r0.z, b1c), fmaf(s1c, r0.w, b1c)));
                    st4(p + PLANE + 4,
                        make_float4(fmaf(s1c, r1.x, b1c), fmaf(s1c, r1.y, b1c),
                                    fmaf(s1c, r1.z, b1c), fmaf(s1c, r1.w, b1c)));
                    st4(p + 2 * PLANE,
                        make_float4(fmaf(s2c, r0.x, b2c), fmaf(s2c, r0.y, b2c),
                                    fmaf(s2c, r0.z, b2c), fmaf(s2c, r0.w, b2c)));
                    st4(p + 2 * PLANE + 4,
                        make_float4(fmaf(s2c, r1.x, b2c), fmaf(s2c, r1.y, b2c),
                                    fmaf(s2c, r1.z, b2c), fmaf(s2c, r1.w, b2c)));
                } else {
                    st4(p, r0);
                    st4(p + 4, r1);
                }
            } else if (i == 0) {
                f0 = r0; f1 = r1;                  // strip-top boundary: hold
            } else if (i == n - 1) {
                l0 = r0; l1 = r1;                  // strip-bottom boundary: hold
            } else {
                // interior: private to this wave; originals live in CUR.m regs.
                float* p = buf + (st0 + i) * WID + (o << 3);
                st4(p, r0);
                st4(p + 4, r1);
            }
        };

        for (int i = 0; i < n; i += 2) {
            do_row(A, B, i);
            if (i + 1 < n) do_row(B, A, i + 1);
        }

        if (!fin) {
            __syncthreads();                       // all strips done reading
            float* p = buf + st0 * WID + (o << 3);
            st4(p, f0);
            st4(p + 4, f1);
            p = buf + (st0 + n - 1) * WID + (o << 3);
            st4(p, l0);
            st4(p + 4, l1);
            __syncthreads();                       // boundary rows visible
        }
    }
}

// ---------------------------------------------------------------------------
// Fallback expand: reads u from usrc (own pixel), writes 3 planes of out.
// ---------------------------------------------------------------------------
__global__ void expand_from(const float* __restrict__ usrc, int ustr,
                            float* __restrict__ out,
                            const float* __restrict__ Wexp,
                            const float* __restrict__ bexp) {
    int idx = blockIdx.x * blockDim.x + threadIdx.x;
    if (idx >= NQUAD) return;
    int b = idx / (PLANE / 4);
    int off = (idx - b * (PLANE / 4)) * 4;

    float4 u = ld4(usrc + (size_t)b * ustr + off);
    float s0 = Wexp[0] + Wexp[1] + Wexp[2];
    float s1 = Wexp[3] + Wexp[4] + Wexp[5];
    float s2 = Wexp[6] + Wexp[7] + Wexp[8];
    float b0 = bexp[0], b1 = bexp[1], b2 = bexp[2];

    size_t base = (size_t)b * BSTRIDE + off;
    st4(out + base, make_float4(fmaf(s0, u.x, b0), fmaf(s0, u.y, b0),
                                fmaf(s0, u.z, b0), fmaf(s0, u.w, b0)));
    st4(out + base + PLANE, make_float4(fmaf(s1, u.x, b1), fmaf(s1, u.y, b1),
                                        fmaf(s1, u.z, b1), fmaf(s1, u.w, b1)));
    st4(out + base + 2 * PLANE, make_float4(fmaf(s2, u.x, b2), fmaf(s2, u.y, b2),
                                            fmaf(s2, u.z, b2), fmaf(s2, u.w, b2)));
}

extern "C" void kernel_launch(void* const* d_in, const int* in_sizes, int n_in,
                              void* d_out, int out_size, void* d_ws, size_t ws_size,
                              hipStream_t stream) {
    const float* x      = (const float*)d_in[0];
    const float* pdelta = (const float*)d_in[1];
    const float* pkappa = (const float*)d_in[2];
    const float* Wexp   = (const float*)d_in[3];
    const float* bexp   = (const float*)d_in[4];
    float* out = (float*)d_out;

    const size_t need = (size_t)2 * NPIX * sizeof(float);   // 64 MB
    if (ws_size >= need) {
        // 8 dispatches: [lum+steps1-4], 6x[4 steps] (5-28), [steps29-30+expand].
        float* uA = (float*)d_ws;
        float* uB = uA + NPIX;
        pm_fusedk<0, 4><<<FBLOCKS, FT, 0, stream>>>(
            x, BSTRIDE, uA, PLANE, pdelta, pkappa, Wexp, bexp);
        float* s = uA;
        float* d = uB;
        for (int k = 0; k < 6; ++k) {
            pm_fusedk<1, 4><<<FBLOCKS, FT, 0, stream>>>(
                s, PLANE, d, PLANE, pdelta, pkappa, Wexp, bexp);
            float* t = s; s = d; d = t;
        }
        // u28 is in s. Final 2 steps + expand; d_out written exactly once.
        pm_fusedk<2, 2><<<FBLOCKS, FT, 0, stream>>>(
            s, PLANE, out, BSTRIDE, pdelta, pkappa, Wexp, bexp);
    } else {
        // Fallback: ping-pong in d_out planes 0/1, separate expand.
        float* uA = out;            // plane 0
        float* uB = out + PLANE;    // plane 1
        pm_fusedk<0, 4><<<FBLOCKS, FT, 0, stream>>>(
            x, BSTRIDE, uA, BSTRIDE, pdelta, pkappa, Wexp, bexp);
        float* s = uA;
        float* d = uB;
        for (int k = 0; k < 6; ++k) {
            pm_fusedk<1, 4><<<FBLOCKS, FT, 0, stream>>>(
                s, BSTRIDE, d, BSTRIDE, pdelta, pkappa, Wexp, bexp);
            float* t = s; s = d; d = t;
        }
        // u28 in s; 2 more steps into d, then expand from d.
        pm_fusedk<1, 2><<<FBLOCKS, FT, 0, stream>>>(
            s, BSTRIDE, d, BSTRIDE, pdelta, pkappa, Wexp, bexp);
        const int block = 256;
        const int grid_q = (NQUAD + block - 1) / block;
        expand_from<<<grid_q, block, 0, stream>>>(d, BSTRIDE, out, Wexp, bexp);
    }
}